// Round 5
// baseline (913.783 us; speedup 1.0000x reference)
//
#include <hip/hip_runtime.h>

// Q4_0 quantized linear: out[16, 11008] = x[16, 4096] @ ((w_q-8)*w_scale).T + bias
// All fp32; w_q holds int32 nibble values in [0,16).
//
// Two kernels (round-2 compute structure + round-4 atomic-free epilogue):
//   P1: lane=row GEMV, R=2 rows/thread (512 rows/block), CK=128.
//       x chunk staged in LDS as xs[k][t]: inner-loop reads are same-address
//       b128 broadcasts (free). w staged per 64-k sub-chunk, packed to bytes,
//       row stride 17 words (gcd(17,32)=1 -> exactly 2 lanes/bank = free).
//       Round 4 proved inner-loop GLOBAL x reads are latency death (VALUBusy
//       20%, 115 us); LDS broadcast + deep staging bursts is the right shape.
//       Partials -> plain coalesced stores (22.5 MB in ws). No atomics
//       (round 3: 90 MB HBM RMW write-through + contended drain).
//   P2: reduce 32 split planes + bias -> out. Fully overwrites d_out, so no
//       memset node needed.

constexpr int T       = 16;
constexpr int IN      = 4096;
constexpr int OUT     = 11008;
constexpr int NSCALE  = IN / 32;       // 128 scales per row
constexpr int THREADS = 256;
constexpr int R       = 2;             // rows per thread
constexpr int ROWSB   = THREADS * R;   // 512 rows per block
constexpr int CK      = 128;           // k per block = 4 scale blocks
constexpr int SUBK    = 64;            // k per w-staging sub-chunk
constexpr int SPLITS  = IN / CK;       // 32
constexpr int WSTRIDE = SUBK / 4 + 1;  // 17 words: 2-way bank aliasing = free
constexpr int XPAD    = 20;            // xs row stride floats (80 B, 16B-aligned)

// ---- P1: partial[sb][t][row] = dot over this block's 128-k chunk ------------
__global__ __launch_bounds__(THREADS, 3) void qlinear_p1(
    const int*   __restrict__ w_q,      // [OUT, IN]
    const float* __restrict__ w_scale,  // [OUT, NSCALE]
    const float* __restrict__ x,        // [T, IN]
    float*       __restrict__ partial)  // [SPLITS, T, OUT] (in ws)
{
    __shared__ __align__(16) float xs[CK][XPAD];            // 10 KiB
    __shared__ unsigned int        ws[ROWSB * WSTRIDE];     // 34 KiB

    const int tid  = threadIdx.x;
    const int row0 = blockIdx.x * ROWSB;   // 0..21 (last block ragged)
    const int sb4  = blockIdx.y;           // 0..31
    const int k0   = sb4 * CK;

    // stage x chunk: xs[k][t] = x[t][k0+k]; global side coalesced over k.
    #pragma unroll
    for (int it = 0; it < CK * T / THREADS; ++it) {  // 8
        int idx = it * THREADS + tid;
        int t   = idx >> 7;
        int k   = idx & (CK - 1);
        xs[k][t] = x[t * IN + k0 + k];
    }

    // 4 scales per row for this 128-k chunk (16B-aligned float4)
    float4 sc[R];
    #pragma unroll
    for (int r = 0; r < R; ++r) {
        int rg = min(row0 + tid + r * THREADS, OUT - 1);
        sc[r] = *(const float4*)(w_scale + (size_t)rg * NSCALE + sb4 * 4);
    }

    float acc[R][T];
    #pragma unroll
    for (int r = 0; r < R; ++r)
        #pragma unroll
        for (int t = 0; t < T; ++t) acc[r][t] = 0.0f;

    #pragma unroll
    for (int sub = 0; sub < CK / SUBK; ++sub) {   // 2
        if (sub) __syncthreads();   // ws reuse hazard

        // stage w: 512 rows x 64 ints -> packed bytes. flat int4 id f:
        // rr=f/16, j=f%16; 16 lanes cover 256 contiguous bytes of one row.
        #pragma unroll 4
        for (int it = 0; it < (ROWSB * SUBK / 4) / THREADS; ++it) {  // 32
            int f  = it * THREADS + tid;
            int rr = f >> 4;
            int j  = f & 15;
            int rg = min(row0 + rr, OUT - 1);
            int4 v = *(const int4*)(w_q + (size_t)rg * IN + k0 + sub * SUBK + j * 4);
            ws[rr * WSTRIDE + j] = (unsigned)v.x | ((unsigned)v.y << 8) |
                                   ((unsigned)v.z << 16) | ((unsigned)v.w << 24);
        }
        __syncthreads();   // staging -> compute (covers xs on first trip)

        #pragma unroll
        for (int kb = 0; kb < 2; ++kb) {   // scale blocks within sub
            float sv[R], s8[R];
            #pragma unroll
            for (int r = 0; r < R; ++r) {
                int sbi = sub * 2 + kb;    // 0..3, compile-time constant
                float s = (sbi == 0) ? sc[r].x : (sbi == 1) ? sc[r].y
                        : (sbi == 2) ? sc[r].z : sc[r].w;
                sv[r] = s;
                s8[r] = -8.0f * s;         // exact
            }
            for (int k4 = 0; k4 < 8; ++k4) {   // 4 k per packed word
                unsigned q[R];
                #pragma unroll
                for (int r = 0; r < R; ++r)
                    q[r] = ws[(tid + r * THREADS) * WSTRIDE + kb * 8 + k4];

                #pragma unroll
                for (int kk = 0; kk < 4; ++kk) {
                    int kl = sub * SUBK + kb * 32 + k4 * 4 + kk;
                    const float4* xp = (const float4*)&xs[kl][0];
                    float4 a = xp[0], b = xp[1], c = xp[2], d = xp[3];
                    #pragma unroll
                    for (int r = 0; r < R; ++r) {
                        // (q-8)*s single-rounded; extract -> v_cvt_f32_ubyte{kk}
                        float wv = fmaf((float)((q[r] >> (8 * kk)) & 0xffu),
                                        sv[r], s8[r]);
                        acc[r][0]  = fmaf(wv, a.x, acc[r][0]);
                        acc[r][1]  = fmaf(wv, a.y, acc[r][1]);
                        acc[r][2]  = fmaf(wv, a.z, acc[r][2]);
                        acc[r][3]  = fmaf(wv, a.w, acc[r][3]);
                        acc[r][4]  = fmaf(wv, b.x, acc[r][4]);
                        acc[r][5]  = fmaf(wv, b.y, acc[r][5]);
                        acc[r][6]  = fmaf(wv, b.z, acc[r][6]);
                        acc[r][7]  = fmaf(wv, b.w, acc[r][7]);
                        acc[r][8]  = fmaf(wv, c.x, acc[r][8]);
                        acc[r][9]  = fmaf(wv, c.y, acc[r][9]);
                        acc[r][10] = fmaf(wv, c.z, acc[r][10]);
                        acc[r][11] = fmaf(wv, c.w, acc[r][11]);
                        acc[r][12] = fmaf(wv, d.x, acc[r][12]);
                        acc[r][13] = fmaf(wv, d.y, acc[r][13]);
                        acc[r][14] = fmaf(wv, d.z, acc[r][14]);
                        acc[r][15] = fmaf(wv, d.w, acc[r][15]);
                    }
                }
            }
        }
    }

    // plain coalesced stores; each (sb,t,row) owned by exactly one thread
    #pragma unroll
    for (int r = 0; r < R; ++r) {
        int rg = row0 + tid + r * THREADS;
        if (rg < OUT) {
            #pragma unroll
            for (int t = 0; t < T; ++t)
                partial[((size_t)sb4 * T + t) * OUT + rg] = acc[r][t];
        }
    }
}

// ---- P2: out[t][row] = sum_sb partial[sb][t][row] + bias[row] ---------------
__global__ __launch_bounds__(THREADS) void qreduce(
    const float* __restrict__ partial,
    const float* __restrict__ bias,
    float*       __restrict__ out)
{
    int row = blockIdx.x * THREADS + threadIdx.x;  // 43*256 = 11008 exact
    int t   = blockIdx.y;                          // 0..15
    float sum = bias[row];
    #pragma unroll 8
    for (int sb = 0; sb < SPLITS; ++sb)
        sum += partial[((size_t)sb * T + t) * OUT + row];
    out[(size_t)t * OUT + row] = sum;
}

extern "C" void kernel_launch(void* const* d_in, const int* in_sizes, int n_in,
                              void* d_out, int out_size, void* d_ws, size_t ws_size,
                              hipStream_t stream) {
    const float* x       = (const float*)d_in[0];
    const int*   w_q     = (const int*)d_in[1];
    const float* w_scale = (const float*)d_in[2];
    const float* bias    = (const float*)d_in[3];
    float*       out     = (float*)d_out;

    float* partial = (float*)d_ws;   // 32*16*11008 floats = 22.5 MB

    dim3 g1((OUT + ROWSB - 1) / ROWSB, SPLITS);   // 22 x 32 = 704 blocks
    qlinear_p1<<<g1, THREADS, 0, stream>>>(w_q, w_scale, x, partial);

    qreduce<<<dim3(OUT / THREADS, T), THREADS, 0, stream>>>(partial, bias, out);
}